// Round 7
// baseline (294.621 us; speedup 1.0000x reference)
//
#include <hip/hip_runtime.h>

typedef short short8 __attribute__((ext_vector_type(8)));
typedef float float4v __attribute__((ext_vector_type(4)));
typedef __attribute__((address_space(1))) const unsigned int gu32;
typedef __attribute__((address_space(3))) unsigned int lu32;

__device__ __forceinline__ unsigned short f2bf(float f) {
  unsigned int u = __builtin_bit_cast(unsigned int, f);
  u += 0x7FFFu + ((u >> 16) & 1u);   // round-to-nearest-even
  return (unsigned short)(u >> 16);
}
__device__ __forceinline__ float bf2f(unsigned short s) {
  return __builtin_bit_cast(float, (unsigned int)s << 16);
}

// Fused prep: blocks [0,4096) = cvt_x rows; blocks [4096, 4096+21512) = weight
// transposes + z conversion.
__global__ __launch_bounds__(256) void prep_fused(
    const float* __restrict__ x,
    const float* __restrict__ z,
    const float* __restrict__ ww1, const float* __restrict__ ww2,
    const float* __restrict__ bw1, const float* __restrict__ bw2,
    unsigned short* __restrict__ xs, unsigned short* __restrict__ xz,
    float* __restrict__ rs,
    unsigned short* __restrict__ w1T, unsigned short* __restrict__ w2T,
    unsigned short* __restrict__ b1T, unsigned short* __restrict__ b2T,
    unsigned short* __restrict__ zb)
{
  if (blockIdx.x < 4096) {
    __shared__ float red[4];
    long long r = blockIdx.x;
    const float* xr = x + r * 4096;
    int t0 = threadIdx.x * 16;
    float v[17];
    const float4* xr4 = (const float4*)(xr + t0);
#pragma unroll
    for (int q = 0; q < 4; ++q) {
      float4 f = xr4[q];
      v[q * 4] = f.x; v[q * 4 + 1] = f.y; v[q * 4 + 2] = f.z; v[q * 4 + 3] = f.w;
    }
    v[16] = (t0 + 16 < 4096) ? xr[t0 + 16] : 0.f;
    unsigned int spk[8], zpk[8];
    float sum = 0.f;
#pragma unroll
    for (int q = 0; q < 8; ++q) {
      unsigned short s0 = f2bf(v[2 * q + 1]);
      unsigned short s1 = f2bf(v[2 * q + 2]);
      sum += bf2f(s0);
      sum += bf2f(s1);
      spk[q] = (unsigned int)s0 | ((unsigned int)s1 << 16);
      unsigned short z0 = (t0 == 0 && q == 0) ? (unsigned short)0 : f2bf(v[2 * q]);
      unsigned short z1 = f2bf(v[2 * q + 1]);
      zpk[q] = (unsigned int)z0 | ((unsigned int)z1 << 16);
    }
    *(uint4*)(xs + r * 4096 + t0)     = *(uint4*)(spk);
    *(uint4*)(xs + r * 4096 + t0 + 8) = *(uint4*)(spk + 4);
    *(uint4*)(xz + r * 4096 + t0)     = *(uint4*)(zpk);
    *(uint4*)(xz + r * 4096 + t0 + 8) = *(uint4*)(zpk + 4);
#pragma unroll
    for (int off = 32; off > 0; off >>= 1) sum += __shfl_down(sum, off);
    if ((threadIdx.x & 63) == 0) red[threadIdx.x >> 6] = sum;
    __syncthreads();
    if (threadIdx.x == 0) rs[r] = red[0] + red[1] + red[2] + red[3];
  } else {
    int i = (blockIdx.x - 4096) * 256 + threadIdx.x;
    if (i < 131072) {
      int n = i & 511, k = i >> 9;
      w1T[n * 256 + k] = f2bf(ww1[i]);
    } else if (i < 655360) {
      int j = i - 131072; int n = j & 511, k = j >> 9;
      w2T[n * 1024 + k] = f2bf(ww2[j]);
    } else if (i < 786432) {
      int j = i - 655360; int n = j & 511, k = j >> 9;
      b1T[n * 256 + k] = f2bf(bw1[j]);
    } else if (i < 1310720) {
      int j = i - 786432; int n = j & 511, k = j >> 9;
      b2T[n * 1024 + k] = f2bf(bw2[j]);
    } else {
      int j = i - 1310720;
      zb[j] = f2bf(z[j]);
    }
  }
}

// Gsum = p0 (+ p1 [+ p2 + p3]), bf16, in-place into p0. 8 elems/thread.
__global__ __launch_bounds__(256) void reduce_p(
    unsigned short* __restrict__ p0, const unsigned short* __restrict__ p1,
    const unsigned short* __restrict__ p2, const unsigned short* __restrict__ p3,
    int nz)
{
  long long i = (long long)(blockIdx.x * 256 + threadIdx.x) * 8;
  short8 a0 = *(const short8*)(p0 + i);
  short8 a1 = *(const short8*)(p1 + i);
  unsigned short st[8];
  if (nz == 4) {
    short8 a2 = *(const short8*)(p2 + i);
    short8 a3 = *(const short8*)(p3 + i);
#pragma unroll
    for (int j = 0; j < 8; ++j)
      st[j] = f2bf((bf2f((unsigned short)a0[j]) + bf2f((unsigned short)a1[j]))
                 + (bf2f((unsigned short)a2[j]) + bf2f((unsigned short)a3[j])));
  } else {
#pragma unroll
    for (int j = 0; j < 8; ++j)
      st[j] = f2bf(bf2f((unsigned short)a0[j]) + bf2f((unsigned short)a1[j]));
  }
  *(uint4*)(p0 + i) = *(const uint4*)(st);
}

// Unified GEMM, BK=32*NH (NH 32-chunks per barrier pair), glds(16B) staging,
// XOR-swizzled unpadded LDS.
// C[r,n] = act(biasv[n] + sum_k Ae[base(r)+kOff+k] * Bt[((n)&bRowMask)*Ktot + bOffB + kOff + k])
// base(r) = (r + (r/RPB)*EXTRA) * BSCALE;  Ae = (nHalf && n0>=nHalf) ? A2 : A.
// SPLITK: blockIdx.z picks k-chunk; partial -> {outp,outp2,pc,pd}[z] (bf16).
// TRANS store: out[bb*outBatchStride + (n0+f)*outLd + t_local] (bf16, LDS repack).
template<int BM, int BN, bool RELU, bool OBF16, bool TRANS, bool SPLITK, int NH>
__global__ __launch_bounds__(256)
void gemm_bt(const unsigned short* __restrict__ A,
             const unsigned short* __restrict__ A2,
             const unsigned short* __restrict__ Bt,
             const float* __restrict__ biasv,
             void* __restrict__ outp,
             void* __restrict__ outp2,
             void* __restrict__ pc,
             void* __restrict__ pd,
             int M, int Kchunk, int RPB, int EXTRA, int BSCALE,
             int nHalf, int bRowMask,
             long long bStrideB, long long outBatchStride, int outLd)
{
  constexpr int WM = BM / 2, WN = BN / 2;
  constexpr int NI = WM / 16, NJ = WN / 16;
  constexpr int AI = BM / 64;                 // glds instrs per wave per 32-chunk
  constexpr int BI = BN / 64;
  constexpr int SA1 = BM * 32, SB1 = BN * 32; // one 32-chunk region (shorts)
  constexpr int STAGE = NH * (SA1 + SB1);
  constexpr int SMEMN = TRANS ? ((128 * 136 > STAGE) ? 128 * 136 : STAGE) : STAGE;
  __shared__ unsigned short smem[SMEMN];
  unsigned short* sB0 = smem + NH * SA1;

  const int tid  = threadIdx.x;
  const int lane = tid & 63;
  const int wave = tid >> 6;
  const int wm = wave >> 1, wn = wave & 1;
  const int lr = lane & 15, quad = lane >> 4;

  const int r0 = blockIdx.x * BM;
  const int n0 = blockIdx.y * BN;
  const int bb = r0 / RPB;
  const int Ktot = SPLITK ? Kchunk * gridDim.z : Kchunk;
  const int kOff = SPLITK ? blockIdx.z * Kchunk : 0;
  const long long bOffB = (long long)bb * bStrideB;
  const unsigned short* Ae = (nHalf && n0 >= nHalf) ? A2 : A;

  const int srow = lane >> 2;
  const int sg = (lane & 3) ^ (srow & 3);     // XOR swizzle on fetch side
  const unsigned short* gA[AI]; unsigned short* ldsA[AI];
#pragma unroll
  for (int c = 0; c < AI; ++c) {
    int instr = c * 4 + wave;
    int row = instr * 16 + srow;
    int r = r0 + row; if (r > M - 1) r = M - 1;          // clamp partial tiles
    gA[c] = Ae + ((long long)r + (long long)(r / RPB) * EXTRA) * BSCALE + kOff + sg * 8;
    ldsA[c] = smem + instr * 512;
  }
  const unsigned short* gB[BI]; unsigned short* ldsB[BI];
#pragma unroll
  for (int c = 0; c < BI; ++c) {
    int instr = c * 4 + wave;
    int row = instr * 16 + srow;
    gB[c] = Bt + (long long)((n0 + row) & bRowMask) * Ktot + bOffB + kOff + sg * 8;
    ldsB[c] = sB0 + instr * 512;
  }

  int aoff[NI], boff[NJ];
#pragma unroll
  for (int i = 0; i < NI; ++i) {
    int rr = wm * WM + i * 16 + lr;
    aoff[i] = rr * 32 + ((quad ^ (rr & 3)) * 8);
  }
#pragma unroll
  for (int j = 0; j < NJ; ++j) {
    int rr = wn * WN + j * 16 + lr;
    boff[j] = rr * 32 + ((quad ^ (rr & 3)) * 8);
  }

  float4v acc[NI][NJ];
  const float4v z4 = {0.f, 0.f, 0.f, 0.f};
#pragma unroll
  for (int i = 0; i < NI; ++i)
#pragma unroll
    for (int j = 0; j < NJ; ++j) acc[i][j] = z4;

  for (int k0 = 0; k0 < Kchunk; k0 += 32 * NH) {
#pragma unroll
    for (int h = 0; h < NH; ++h) {
#pragma unroll
      for (int c = 0; c < AI; ++c)
        __builtin_amdgcn_global_load_lds((gu32*)(gA[c] + k0 + h * 32),
                                         (lu32*)(ldsA[c] + h * SA1), 16, 0, 0);
#pragma unroll
      for (int c = 0; c < BI; ++c)
        __builtin_amdgcn_global_load_lds((gu32*)(gB[c] + k0 + h * 32),
                                         (lu32*)(ldsB[c] + h * SB1), 16, 0, 0);
    }
    __syncthreads();
#pragma unroll
    for (int h = 0; h < NH; ++h) {
      short8 af[NI], bfr[NJ];
#pragma unroll
      for (int i = 0; i < NI; ++i) af[i] = *(const short8*)(smem + h * SA1 + aoff[i]);
#pragma unroll
      for (int j = 0; j < NJ; ++j) bfr[j] = *(const short8*)(sB0 + h * SB1 + boff[j]);
#pragma unroll
      for (int i = 0; i < NI; ++i)
#pragma unroll
        for (int j = 0; j < NJ; ++j)
          acc[i][j] = __builtin_amdgcn_mfma_f32_16x16x32_bf16(af[i], bfr[j], acc[i][j], 0, 0, 0);
    }
    __syncthreads();
  }

  if (TRANS) {
    // repack D (t,f) -> LDS (f-major, stride 136), then coalesced b128 stores
    unsigned short* Ts = smem;
#pragma unroll
    for (int j = 0; j < NJ; ++j) {
      int fr = wn * WN + j * 16 + lr;
      float bv = biasv[n0 + fr];
#pragma unroll
      for (int i = 0; i < NI; ++i) {
        int tr = wm * WM + i * 16 + quad * 4;
        unsigned long long pk = 0;
#pragma unroll
        for (int g = 0; g < 4; ++g) {
          float vv = acc[i][j][g] + bv;
          if (RELU) vv = fmaxf(vv, 0.f);
          pk |= (unsigned long long)f2bf(vv) << (16 * g);
        }
        *(unsigned long long*)(Ts + fr * 136 + tr) = pk;
      }
    }
    __syncthreads();
    int fr = tid >> 1, sgg = tid & 1;
    int t0l = r0 - bb * RPB;
    unsigned short* dst = (unsigned short*)outp + (long long)bb * outBatchStride
                        + (long long)(n0 + fr) * outLd + t0l + sgg * 64;
    const unsigned short* srcp = Ts + fr * 136 + sgg * 64;
#pragma unroll
    for (int u = 0; u < 8; ++u)
      *(uint4*)(dst + u * 8) = *(const uint4*)(srcp + u * 8);
  } else {
    void* op = outp;
    if (SPLITK) {
      int zz = blockIdx.z;
      op = (zz == 0) ? outp : (zz == 1) ? outp2 : (zz == 2) ? pc : pd;
    }
#pragma unroll
    for (int j = 0; j < NJ; ++j) {
      int n_g = n0 + wn * WN + j * 16 + lr;
      float bv = biasv ? biasv[n_g] : 0.f;
#pragma unroll
      for (int i = 0; i < NI; ++i) {
        int r_base = r0 + wm * WM + i * 16 + quad * 4;
#pragma unroll
        for (int g = 0; g < 4; ++g) {
          int r_g = r_base + g;
          if (r_g >= M) continue;
          float v = acc[i][j][g] + bv;
          if (RELU) v = fmaxf(v, 0.f);
          long long oidx = (long long)r_g * outLd + n_g;
          if (OBF16) ((unsigned short*)op)[oidx] = f2bf(v);
          else       ((float*)op)[oidx] = v;
        }
      }
    }
  }
}

// Fused final, 2 K-segments (K=2048):
//   k in [0,1024):    A=Gsum[r,k],               B=w2T[n,k]
//   k in [1024,2048): A=h1b[(r+r/512)*512+k'],   B=b2T[n,k']     (k'=k-1024)
// out[r,n] = acc + rs[r]*wb2[n] + bb2[n].  BM=BN=64, BK=64, glds staging.
__global__ __launch_bounds__(256) void final_gemm3(
    const unsigned short* __restrict__ Gsum,
    const unsigned short* __restrict__ h1b,
    const unsigned short* __restrict__ w2T,
    const unsigned short* __restrict__ b2T,
    const float* __restrict__ rs,
    const float* __restrict__ wb2,
    const float* __restrict__ bb2,
    float* __restrict__ out)
{
  constexpr int SA1 = 64 * 32, SB1 = 64 * 32;
  __shared__ unsigned short smem[2 * SA1 + 2 * SB1];
  const int tid = threadIdx.x;
  const int lane = tid & 63, wave = tid >> 6;
  const int wm = wave >> 1, wn = wave & 1;
  const int lr = lane & 15, quad = lane >> 4;
  const int r0 = blockIdx.x * 64, n0 = blockIdx.y * 64;

  const int srow = lane >> 2;
  const int sg = (lane & 3) ^ (srow & 3);
  const int row = wave * 16 + srow;
  const int rA = r0 + row;
  const int rB = n0 + row;
  const unsigned short* aP[2] = {
    Gsum + (long long)rA * 1024 + sg * 8,
    h1b + ((long long)rA + (rA >> 9)) * 512 + sg * 8 };
  const unsigned short* bP[2] = {
    w2T + (long long)rB * 1024 + sg * 8,
    b2T + (long long)rB * 1024 + sg * 8 };
  unsigned short* ldsA = smem + wave * 512;
  unsigned short* ldsB = smem + 2 * SA1 + wave * 512;

  int aoff[2], boff[2];
#pragma unroll
  for (int i = 0; i < 2; ++i) {
    int rr = wm * 32 + i * 16 + lr;
    aoff[i] = rr * 32 + ((quad ^ (rr & 3)) * 8);
    int nn = wn * 32 + i * 16 + lr;
    boff[i] = 2 * SA1 + nn * 32 + ((quad ^ (nn & 3)) * 8);
  }

  float4v acc[2][2];
  const float4v z4 = {0.f, 0.f, 0.f, 0.f};
  acc[0][0] = z4; acc[0][1] = z4; acc[1][0] = z4; acc[1][1] = z4;

  for (int k0 = 0; k0 < 2048; k0 += 64) {
    int seg = k0 >> 10;
    int kk = k0 & 1023;
#pragma unroll
    for (int h = 0; h < 2; ++h) {
      __builtin_amdgcn_global_load_lds((gu32*)(aP[seg] + kk + h * 32),
                                       (lu32*)(ldsA + h * SA1), 16, 0, 0);
      __builtin_amdgcn_global_load_lds((gu32*)(bP[seg] + kk + h * 32),
                                       (lu32*)(ldsB + h * SB1), 16, 0, 0);
    }
    __syncthreads();
#pragma unroll
    for (int h = 0; h < 2; ++h) {
      short8 af[2], bfr[2];
      af[0] = *(const short8*)(smem + h * SA1 + aoff[0]);
      af[1] = *(const short8*)(smem + h * SA1 + aoff[1]);
      bfr[0] = *(const short8*)(smem + h * SB1 + boff[0]);
      bfr[1] = *(const short8*)(smem + h * SB1 + boff[1]);
#pragma unroll
      for (int i = 0; i < 2; ++i)
#pragma unroll
        for (int j = 0; j < 2; ++j)
          acc[i][j] = __builtin_amdgcn_mfma_f32_16x16x32_bf16(af[i], bfr[j], acc[i][j], 0, 0, 0);
    }
    __syncthreads();
  }

#pragma unroll
  for (int j = 0; j < 2; ++j) {
    int n_g = n0 + wn * 32 + j * 16 + lr;
    float w2b = wb2[n_g], bbv = bb2[n_g];
#pragma unroll
    for (int i = 0; i < 2; ++i) {
      int rb = r0 + wm * 32 + i * 16 + quad * 4;
#pragma unroll
      for (int g = 0; g < 4; ++g) {
        int r_g = rb + g;
        out[(long long)r_g * 512 + n_g] = acc[i][j][g] + rs[r_g] * w2b + bbv;
      }
    }
  }
}

extern "C" void kernel_launch(void* const* d_in, const int* in_sizes, int n_in,
                              void* d_out, int out_size, void* d_ws, size_t ws_size,
                              hipStream_t stream) {
  const float* x   = (const float*)d_in[0];
  const float* z   = (const float*)d_in[1];
  const float* ww1 = (const float*)d_in[2];
  const float* wb1 = (const float*)d_in[3];
  const float* ww2 = (const float*)d_in[4];
  const float* wb2 = (const float*)d_in[5];
  const float* bw1 = (const float*)d_in[6];
  const float* bb1 = (const float*)d_in[7];
  const float* bw2 = (const float*)d_in[8];
  const float* bb2 = (const float*)d_in[9];

  char* ws = (char*)d_ws;
  unsigned short* xs  = (unsigned short*)ws; ws += 16777216ll * 2;  // (4096,4096) shifted bf16
  unsigned short* xz  = (unsigned short*)ws; ws += 16777216ll * 2;  // (4096,4096) t0-zeroed bf16
  unsigned short* zb  = (unsigned short*)ws; ws += 4196352ll  * 2;  // (8,4098,128) bf16; reused as p0
  unsigned short* h1T = (unsigned short*)ws; ws += 16777216ll * 2;  // (8,512,4096) h1 transposed bf16
  unsigned short* h1b = (unsigned short*)ws; ws += 2101248ll  * 2;  // (8,513,512) bias-path h1 bf16
  unsigned short* w2T = (unsigned short*)ws; ws += 524288ll * 2;    // (512,1024)
  unsigned short* b2T = (unsigned short*)ws; ws += 524288ll * 2;
  float* rs = (float*)ws;                    ws += 4096ll * 4;      // rowsum(xs)
  char* tail = ws;
  // w1T/b1T live until conv1-b completes, then tail becomes p1..p3
  unsigned short* w1T = (unsigned short*)tail;                      // (512,256)
  unsigned short* b1T = (unsigned short*)tail + 131072;             // (512,256)
  unsigned short* p0  = zb;                                         // (4096,1024) bf16 (zb dead by then)
  unsigned short* p1  = (unsigned short*)tail;                      // (4096,1024) bf16
  unsigned short* p2  = (unsigned short*)(tail + 8388608);
  unsigned short* p3  = (unsigned short*)(tail + 16777216);

  size_t fixed = (size_t)(tail - (char*)d_ws);
  int nz = (ws_size >= fixed + 3ull * 8388608) ? 4 : 2;             // split-K factor for G

  prep_fused<<<4096 + 21512, 256, 0, stream>>>(
      x, z, ww1, ww2, bw1, bw2, xs, xz, rs, w1T, w2T, b1T, b2T, zb);

  // conv1-w -> h1T (TRANS, relu, BK=128): M=8*4096, K=256, A row = (r + 2b)*128
  gemm_bt<128, 128, true, true, true, false, 4><<<dim3(256, 4), 256, 0, stream>>>(
      zb, nullptr, w1T, wb1, h1T, nullptr, nullptr, nullptr,
      32768, 256, 4096, 2, 128, 0, 0xFFFF, 0, 512ll * 4096, 4096);
  // conv1-b (t<513): M=8*513, A row = (r + 3585b)*128 -> h1b bf16
  gemm_bt<64, 128, true, true, false, false, 2><<<dim3(65, 4), 256, 0, stream>>>(
      zb, nullptr, b1T, bb1, h1b, nullptr, nullptr, nullptr,
      4104, 256, 513, 3585, 128, 0, 0xFFFF, 0, 0, 512);
  // G = [xs ; xz] @ h1T^T, 128^2 tiles, split-K x nz -> p0..p{nz-1} (bf16):
  // M=4096, N=1024, Ktot=4096; B per-batch rows, bRowMask=511
  gemm_bt<128, 128, false, true, false, true, 2><<<dim3(32, 8, nz), 256, 0, stream>>>(
      xs, xz, h1T, nullptr, p0, p1, p2, p3,
      4096, 4096 / nz, 512, 0, 4096, 512, 511, 512ll * 4096, 0, 1024);
  // Gsum = sum of partials (in place into p0)
  reduce_p<<<2048, 256, 0, stream>>>(p0, p1, p2, p3, nz);
  // out = Gsum @ w2 + h1b-pair @ b2 + rs x wb2 + bb2  (K=2048 fused)
  final_gemm3<<<dim3(64, 8), 256, 0, stream>>>(
      p0, h1b, w2T, b2T, rs, wb2, bb2, (float*)d_out);
}

// Round 8
// 275.381 us; speedup vs baseline: 1.0699x; 1.0699x over previous
//
#include <hip/hip_runtime.h>

typedef short short8 __attribute__((ext_vector_type(8)));
typedef float float4v __attribute__((ext_vector_type(4)));
typedef __attribute__((address_space(1))) const unsigned int gu32;
typedef __attribute__((address_space(3))) unsigned int lu32;

__device__ __forceinline__ unsigned short f2bf(float f) {
  unsigned int u = __builtin_bit_cast(unsigned int, f);
  u += 0x7FFFu + ((u >> 16) & 1u);   // round-to-nearest-even
  return (unsigned short)(u >> 16);
}
__device__ __forceinline__ float bf2f(unsigned short s) {
  return __builtin_bit_cast(float, (unsigned int)s << 16);
}

// Fused prep: blocks [0,4096) = cvt_x rows; blocks [4096, 4096+21512) = weight
// transposes + z conversion.
__global__ __launch_bounds__(256) void prep_fused(
    const float* __restrict__ x,
    const float* __restrict__ z,
    const float* __restrict__ ww1, const float* __restrict__ ww2,
    const float* __restrict__ bw1, const float* __restrict__ bw2,
    unsigned short* __restrict__ xs, unsigned short* __restrict__ xz,
    float* __restrict__ rs,
    unsigned short* __restrict__ w1T, unsigned short* __restrict__ w2T,
    unsigned short* __restrict__ b1T, unsigned short* __restrict__ b2T,
    unsigned short* __restrict__ zb)
{
  if (blockIdx.x < 4096) {
    __shared__ float red[4];
    long long r = blockIdx.x;
    const float* xr = x + r * 4096;
    int t0 = threadIdx.x * 16;
    float v[17];
    const float4* xr4 = (const float4*)(xr + t0);
#pragma unroll
    for (int q = 0; q < 4; ++q) {
      float4 f = xr4[q];
      v[q * 4] = f.x; v[q * 4 + 1] = f.y; v[q * 4 + 2] = f.z; v[q * 4 + 3] = f.w;
    }
    v[16] = (t0 + 16 < 4096) ? xr[t0 + 16] : 0.f;
    unsigned int spk[8], zpk[8];
    float sum = 0.f;
#pragma unroll
    for (int q = 0; q < 8; ++q) {
      unsigned short s0 = f2bf(v[2 * q + 1]);
      unsigned short s1 = f2bf(v[2 * q + 2]);
      sum += bf2f(s0);
      sum += bf2f(s1);
      spk[q] = (unsigned int)s0 | ((unsigned int)s1 << 16);
      unsigned short z0 = (t0 == 0 && q == 0) ? (unsigned short)0 : f2bf(v[2 * q]);
      unsigned short z1 = f2bf(v[2 * q + 1]);
      zpk[q] = (unsigned int)z0 | ((unsigned int)z1 << 16);
    }
    *(uint4*)(xs + r * 4096 + t0)     = *(uint4*)(spk);
    *(uint4*)(xs + r * 4096 + t0 + 8) = *(uint4*)(spk + 4);
    *(uint4*)(xz + r * 4096 + t0)     = *(uint4*)(zpk);
    *(uint4*)(xz + r * 4096 + t0 + 8) = *(uint4*)(zpk + 4);
#pragma unroll
    for (int off = 32; off > 0; off >>= 1) sum += __shfl_down(sum, off);
    if ((threadIdx.x & 63) == 0) red[threadIdx.x >> 6] = sum;
    __syncthreads();
    if (threadIdx.x == 0) rs[r] = red[0] + red[1] + red[2] + red[3];
  } else {
    int i = (blockIdx.x - 4096) * 256 + threadIdx.x;
    if (i < 131072) {
      int n = i & 511, k = i >> 9;
      w1T[n * 256 + k] = f2bf(ww1[i]);
    } else if (i < 655360) {
      int j = i - 131072; int n = j & 511, k = j >> 9;
      w2T[n * 1024 + k] = f2bf(ww2[j]);
    } else if (i < 786432) {
      int j = i - 655360; int n = j & 511, k = j >> 9;
      b1T[n * 256 + k] = f2bf(bw1[j]);
    } else if (i < 1310720) {
      int j = i - 786432; int n = j & 511, k = j >> 9;
      b2T[n * 1024 + k] = f2bf(bw2[j]);
    } else {
      int j = i - 1310720;
      zb[j] = f2bf(z[j]);
    }
  }
}

// Unified GEMM, BK=32*NH (NH 32-chunks per barrier pair), glds(16B) staging,
// XOR-swizzled unpadded LDS.
// C[r,n] = act(biasv[n] + sum_k Ae[base(r)+kOff+k] * Bt[((n)&bRowMask)*Ktot + bOffB + kOff + k])
// base(r) = (r + (r/RPB)*EXTRA) * BSCALE;  Ae = (nHalf && n0>=nHalf) ? A2 : A.
// SPLITK: blockIdx.z picks k-chunk; partial -> outp/outp2 (bf16).
// TRANS store: out[bb*outBatchStride + (n0+f)*outLd + t_local] (bf16, LDS repack).
template<int BM, int BN, bool RELU, bool OBF16, bool TRANS, bool SPLITK, int NH>
__global__ __launch_bounds__(256)
void gemm_bt(const unsigned short* __restrict__ A,
             const unsigned short* __restrict__ A2,
             const unsigned short* __restrict__ Bt,
             const float* __restrict__ biasv,
             void* __restrict__ outp,
             void* __restrict__ outp2,
             int M, int Kchunk, int RPB, int EXTRA, int BSCALE,
             int nHalf, int bRowMask,
             long long bStrideB, long long outBatchStride, int outLd)
{
  constexpr int WM = BM / 2, WN = BN / 2;
  constexpr int NI = WM / 16, NJ = WN / 16;
  constexpr int AI = BM / 64;                 // glds instrs per wave per 32-chunk
  constexpr int BI = BN / 64;
  constexpr int SA1 = BM * 32, SB1 = BN * 32; // one 32-chunk region (shorts)
  constexpr int STAGE = NH * (SA1 + SB1);
  constexpr int SMEMN = TRANS ? ((128 * 136 > STAGE) ? 128 * 136 : STAGE) : STAGE;
  __shared__ unsigned short smem[SMEMN];
  unsigned short* sB0 = smem + NH * SA1;

  const int tid  = threadIdx.x;
  const int lane = tid & 63;
  const int wave = tid >> 6;
  const int wm = wave >> 1, wn = wave & 1;
  const int lr = lane & 15, quad = lane >> 4;

  const int r0 = blockIdx.x * BM;
  const int n0 = blockIdx.y * BN;
  const int bb = r0 / RPB;
  const int Ktot = SPLITK ? Kchunk * gridDim.z : Kchunk;
  const int kOff = SPLITK ? blockIdx.z * Kchunk : 0;
  const long long bOffB = (long long)bb * bStrideB;
  const unsigned short* Ae = (nHalf && n0 >= nHalf) ? A2 : A;

  const int srow = lane >> 2;
  const int sg = (lane & 3) ^ (srow & 3);     // XOR swizzle on fetch side
  const unsigned short* gA[AI]; unsigned short* ldsA[AI];
#pragma unroll
  for (int c = 0; c < AI; ++c) {
    int instr = c * 4 + wave;
    int row = instr * 16 + srow;
    int r = r0 + row; if (r > M - 1) r = M - 1;          // clamp partial tiles
    gA[c] = Ae + ((long long)r + (long long)(r / RPB) * EXTRA) * BSCALE + kOff + sg * 8;
    ldsA[c] = smem + instr * 512;
  }
  const unsigned short* gB[BI]; unsigned short* ldsB[BI];
#pragma unroll
  for (int c = 0; c < BI; ++c) {
    int instr = c * 4 + wave;
    int row = instr * 16 + srow;
    gB[c] = Bt + (long long)((n0 + row) & bRowMask) * Ktot + bOffB + kOff + sg * 8;
    ldsB[c] = sB0 + instr * 512;
  }

  int aoff[NI], boff[NJ];
#pragma unroll
  for (int i = 0; i < NI; ++i) {
    int rr = wm * WM + i * 16 + lr;
    aoff[i] = rr * 32 + ((quad ^ (rr & 3)) * 8);
  }
#pragma unroll
  for (int j = 0; j < NJ; ++j) {
    int rr = wn * WN + j * 16 + lr;
    boff[j] = rr * 32 + ((quad ^ (rr & 3)) * 8);
  }

  float4v acc[NI][NJ];
  const float4v z4 = {0.f, 0.f, 0.f, 0.f};
#pragma unroll
  for (int i = 0; i < NI; ++i)
#pragma unroll
    for (int j = 0; j < NJ; ++j) acc[i][j] = z4;

  for (int k0 = 0; k0 < Kchunk; k0 += 32 * NH) {
#pragma unroll
    for (int h = 0; h < NH; ++h) {
#pragma unroll
      for (int c = 0; c < AI; ++c)
        __builtin_amdgcn_global_load_lds((gu32*)(gA[c] + k0 + h * 32),
                                         (lu32*)(ldsA[c] + h * SA1), 16, 0, 0);
#pragma unroll
      for (int c = 0; c < BI; ++c)
        __builtin_amdgcn_global_load_lds((gu32*)(gB[c] + k0 + h * 32),
                                         (lu32*)(ldsB[c] + h * SB1), 16, 0, 0);
    }
    __syncthreads();
#pragma unroll
    for (int h = 0; h < NH; ++h) {
      short8 af[NI], bfr[NJ];
#pragma unroll
      for (int i = 0; i < NI; ++i) af[i] = *(const short8*)(smem + h * SA1 + aoff[i]);
#pragma unroll
      for (int j = 0; j < NJ; ++j) bfr[j] = *(const short8*)(sB0 + h * SB1 + boff[j]);
#pragma unroll
      for (int i = 0; i < NI; ++i)
#pragma unroll
        for (int j = 0; j < NJ; ++j)
          acc[i][j] = __builtin_amdgcn_mfma_f32_16x16x32_bf16(af[i], bfr[j], acc[i][j], 0, 0, 0);
    }
    __syncthreads();
  }

  if (TRANS) {
    // repack D (t,f) -> LDS (f-major, stride 136), then coalesced b128 stores
    unsigned short* Ts = smem;
#pragma unroll
    for (int j = 0; j < NJ; ++j) {
      int fr = wn * WN + j * 16 + lr;
      float bv = biasv[n0 + fr];
#pragma unroll
      for (int i = 0; i < NI; ++i) {
        int tr = wm * WM + i * 16 + quad * 4;
        unsigned long long pk = 0;
#pragma unroll
        for (int g = 0; g < 4; ++g) {
          float vv = acc[i][j][g] + bv;
          if (RELU) vv = fmaxf(vv, 0.f);
          pk |= (unsigned long long)f2bf(vv) << (16 * g);
        }
        *(unsigned long long*)(Ts + fr * 136 + tr) = pk;
      }
    }
    __syncthreads();
    int fr = tid >> 1, sgg = tid & 1;
    int t0l = r0 - bb * RPB;
    unsigned short* dst = (unsigned short*)outp + (long long)bb * outBatchStride
                        + (long long)(n0 + fr) * outLd + t0l + sgg * 64;
    const unsigned short* srcp = Ts + fr * 136 + sgg * 64;
#pragma unroll
    for (int u = 0; u < 8; ++u)
      *(uint4*)(dst + u * 8) = *(const uint4*)(srcp + u * 8);
  } else {
    void* op = (SPLITK && blockIdx.z) ? outp2 : outp;
#pragma unroll
    for (int j = 0; j < NJ; ++j) {
      int n_g = n0 + wn * WN + j * 16 + lr;
      float bv = biasv ? biasv[n_g] : 0.f;
#pragma unroll
      for (int i = 0; i < NI; ++i) {
        int r_base = r0 + wm * WM + i * 16 + quad * 4;
#pragma unroll
        for (int g = 0; g < 4; ++g) {
          int r_g = r_base + g;
          if (r_g >= M) continue;
          float v = acc[i][j][g] + bv;
          if (RELU) v = fmaxf(v, 0.f);
          long long oidx = (long long)r_g * outLd + n_g;
          if (OBF16) ((unsigned short*)op)[oidx] = f2bf(v);
          else       ((float*)op)[oidx] = v;
        }
      }
    }
  }
}

// Fused final, 3 K-segments (K=3072), BK=128 (NH=4):
//   k in [0,1024):    A=p0[r,k],                 B=w2T[n,k]
//   k in [1024,2048): A=p1[r,k-1024],            B=w2T[n,k-1024]
//   k in [2048,3072): A=h1b[(r+r/512)*512+k'],   B=b2T[n,k']     (k'=k-2048)
// out[r,n] = acc + rs[r]*wb2[n] + bb2[n].  BM=BN=64, glds staging.
__global__ __launch_bounds__(256) void final_gemm3(
    const unsigned short* __restrict__ p0,
    const unsigned short* __restrict__ p1,
    const unsigned short* __restrict__ h1b,
    const unsigned short* __restrict__ w2T,
    const unsigned short* __restrict__ b2T,
    const float* __restrict__ rs,
    const float* __restrict__ wb2,
    const float* __restrict__ bb2,
    float* __restrict__ out)
{
  constexpr int SA1 = 64 * 32, SB1 = 64 * 32;
  __shared__ unsigned short smem[4 * SA1 + 4 * SB1];
  const int tid = threadIdx.x;
  const int lane = tid & 63, wave = tid >> 6;
  const int wm = wave >> 1, wn = wave & 1;
  const int lr = lane & 15, quad = lane >> 4;
  const int r0 = blockIdx.x * 64, n0 = blockIdx.y * 64;

  const int srow = lane >> 2;
  const int sg = (lane & 3) ^ (srow & 3);
  const int row = wave * 16 + srow;
  const int rA = r0 + row;
  const int rB = n0 + row;
  const unsigned short* aP[3] = {
    p0 + (long long)rA * 1024 + sg * 8,
    p1 + (long long)rA * 1024 + sg * 8,
    h1b + ((long long)rA + (rA >> 9)) * 512 + sg * 8 };
  const unsigned short* bP[3] = {
    w2T + (long long)rB * 1024 + sg * 8,
    w2T + (long long)rB * 1024 + sg * 8,
    b2T + (long long)rB * 1024 + sg * 8 };
  unsigned short* ldsA = smem + wave * 512;
  unsigned short* ldsB = smem + 4 * SA1 + wave * 512;

  int aoff[2], boff[2];
#pragma unroll
  for (int i = 0; i < 2; ++i) {
    int rr = wm * 32 + i * 16 + lr;
    aoff[i] = rr * 32 + ((quad ^ (rr & 3)) * 8);
    int nn = wn * 32 + i * 16 + lr;
    boff[i] = 4 * SA1 + nn * 32 + ((quad ^ (nn & 3)) * 8);
  }

  float4v acc[2][2];
  const float4v z4 = {0.f, 0.f, 0.f, 0.f};
  acc[0][0] = z4; acc[0][1] = z4; acc[1][0] = z4; acc[1][1] = z4;

  for (int k0 = 0; k0 < 3072; k0 += 128) {
    int seg = k0 >> 10;
    int kk = k0 & 1023;
#pragma unroll
    for (int h = 0; h < 4; ++h) {
      __builtin_amdgcn_global_load_lds((gu32*)(aP[seg] + kk + h * 32),
                                       (lu32*)(ldsA + h * SA1), 16, 0, 0);
      __builtin_amdgcn_global_load_lds((gu32*)(bP[seg] + kk + h * 32),
                                       (lu32*)(ldsB + h * SB1), 16, 0, 0);
    }
    __syncthreads();
#pragma unroll
    for (int h = 0; h < 4; ++h) {
      short8 af[2], bfr[2];
      af[0] = *(const short8*)(smem + h * SA1 + aoff[0]);
      af[1] = *(const short8*)(smem + h * SA1 + aoff[1]);
      bfr[0] = *(const short8*)(smem + h * SB1 + boff[0]);
      bfr[1] = *(const short8*)(smem + h * SB1 + boff[1]);
#pragma unroll
      for (int i = 0; i < 2; ++i)
#pragma unroll
        for (int j = 0; j < 2; ++j)
          acc[i][j] = __builtin_amdgcn_mfma_f32_16x16x32_bf16(af[i], bfr[j], acc[i][j], 0, 0, 0);
    }
    __syncthreads();
  }

#pragma unroll
  for (int j = 0; j < 2; ++j) {
    int n_g = n0 + wn * 32 + j * 16 + lr;
    float w2b = wb2[n_g], bbv = bb2[n_g];
#pragma unroll
    for (int i = 0; i < 2; ++i) {
      int rb = r0 + wm * 32 + i * 16 + quad * 4;
#pragma unroll
      for (int g = 0; g < 4; ++g) {
        int r_g = rb + g;
        out[(long long)r_g * 512 + n_g] = acc[i][j][g] + rs[r_g] * w2b + bbv;
      }
    }
  }
}

extern "C" void kernel_launch(void* const* d_in, const int* in_sizes, int n_in,
                              void* d_out, int out_size, void* d_ws, size_t ws_size,
                              hipStream_t stream) {
  const float* x   = (const float*)d_in[0];
  const float* z   = (const float*)d_in[1];
  const float* ww1 = (const float*)d_in[2];
  const float* wb1 = (const float*)d_in[3];
  const float* ww2 = (const float*)d_in[4];
  const float* wb2 = (const float*)d_in[5];
  const float* bw1 = (const float*)d_in[6];
  const float* bb1 = (const float*)d_in[7];
  const float* bw2 = (const float*)d_in[8];
  const float* bb2 = (const float*)d_in[9];

  char* ws = (char*)d_ws;
  unsigned short* xs  = (unsigned short*)ws; ws += 16777216ll * 2;  // (4096,4096) shifted bf16
  unsigned short* xz  = (unsigned short*)ws; ws += 16777216ll * 2;  // (4096,4096) t0-zeroed bf16
  unsigned short* zb  = (unsigned short*)ws; ws += 4196352ll  * 2;  // (8,4098,128) bf16; reused as p0
  unsigned short* h1T = (unsigned short*)ws; ws += 16777216ll * 2;  // (8,512,4096) h1 transposed bf16
  unsigned short* h1b = (unsigned short*)ws; ws += 2101248ll  * 2;  // (8,513,512) bias-path h1 bf16
  unsigned short* w2T = (unsigned short*)ws; ws += 524288ll * 2;    // (512,1024)
  unsigned short* b2T = (unsigned short*)ws; ws += 524288ll * 2;
  float* rs = (float*)ws;                    ws += 4096ll * 4;      // rowsum(xs)
  char* tail = ws;
  // w1T/b1T live until conv1-b completes, then tail becomes p1
  unsigned short* w1T = (unsigned short*)tail;                      // (512,256)
  unsigned short* b1T = (unsigned short*)tail + 131072;             // (512,256)
  unsigned short* p0  = zb;                                         // (4096,1024) bf16 (zb dead by then)
  unsigned short* p1  = (unsigned short*)tail;                      // (4096,1024) bf16

  prep_fused<<<4096 + 21512, 256, 0, stream>>>(
      x, z, ww1, ww2, bw1, bw2, xs, xz, rs, w1T, w2T, b1T, b2T, zb);

  // conv1-w -> h1T (TRANS, relu, BK=64 -> 34.8KB LDS, 4 blocks/CU):
  // M=8*4096, K=256, A row = (r + 2b)*128
  gemm_bt<128, 128, true, true, true, false, 2><<<dim3(256, 4), 256, 0, stream>>>(
      zb, nullptr, w1T, wb1, h1T, nullptr,
      32768, 256, 4096, 2, 128, 0, 0xFFFF, 0, 512ll * 4096, 4096);
  // conv1-b (t<513): M=8*513, A row = (r + 3585b)*128 -> h1b bf16
  gemm_bt<64, 128, true, true, false, false, 2><<<dim3(65, 4), 256, 0, stream>>>(
      zb, nullptr, b1T, bb1, h1b, nullptr,
      4104, 256, 513, 3585, 128, 0, 0xFFFF, 0, 0, 512);
  // G = [xs ; xz] @ h1T^T, 128^2 tiles, BK=128 (64KB LDS; grid-capped at 2/CU
  // anyway so no occupancy loss, half the barrier drains), split-K x2 -> p0,p1:
  // M=4096, N=1024, Ktot=4096, Kchunk=2048; B per-batch rows, bRowMask=511
  gemm_bt<128, 128, false, true, false, true, 4><<<dim3(32, 8, 2), 256, 0, stream>>>(
      xs, xz, h1T, nullptr, p0, p1,
      4096, 2048, 512, 0, 4096, 512, 511, 512ll * 4096, 0, 1024);
  // out = p0@w2 + p1@w2 + h1b-pair@b2 + rs x wb2 + bb2  (K=3072 fused, BK=128)
  final_gemm3<<<dim3(64, 8), 256, 0, stream>>>(
      p0, p1, h1b, w2T, b2T, rs, wb2, bb2, (float*)d_out);
}

// Round 9
// 252.184 us; speedup vs baseline: 1.1683x; 1.0920x over previous
//
#include <hip/hip_runtime.h>

typedef short short8 __attribute__((ext_vector_type(8)));
typedef float float4v __attribute__((ext_vector_type(4)));
typedef __attribute__((address_space(1))) const unsigned int gu32;
typedef __attribute__((address_space(3))) unsigned int lu32;

__device__ __forceinline__ unsigned short f2bf(float f) {
  unsigned int u = __builtin_bit_cast(unsigned int, f);
  u += 0x7FFFu + ((u >> 16) & 1u);   // round-to-nearest-even
  return (unsigned short)(u >> 16);
}
__device__ __forceinline__ float bf2f(unsigned short s) {
  return __builtin_bit_cast(float, (unsigned int)s << 16);
}

// prep_w: weight transposes + z conversion (x handled in the megakernel).
__global__ __launch_bounds__(256) void prep_w(
    const float* __restrict__ ww1, const float* __restrict__ ww2,
    const float* __restrict__ bw1, const float* __restrict__ bw2,
    const float* __restrict__ z,
    unsigned short* __restrict__ w1T, unsigned short* __restrict__ w2T,
    unsigned short* __restrict__ b1T, unsigned short* __restrict__ b2T,
    unsigned short* __restrict__ zb)
{
  int i = blockIdx.x * 256 + threadIdx.x;
  if (i < 131072) {
    int n = i & 511, k = i >> 9;
    w1T[n * 256 + k] = f2bf(ww1[i]);
  } else if (i < 655360) {
    int j = i - 131072; int n = j & 511, k = j >> 9;
    w2T[n * 1024 + k] = f2bf(ww2[j]);
  } else if (i < 786432) {
    int j = i - 655360; int n = j & 511, k = j >> 9;
    b1T[n * 256 + k] = f2bf(bw1[j]);
  } else if (i < 1310720) {
    int j = i - 786432; int n = j & 511, k = j >> 9;
    b2T[n * 1024 + k] = f2bf(bw2[j]);
  } else {
    int j = i - 1310720;
    zb[j] = f2bf(z[j]);
  }
}

// Unified GEMM core, BK=32*NH, glds(16B) staging, XOR-swizzled unpadded LDS.
// C[r,n] = act(biasv[n] + sum_k Ae[base(r)+kOff+k] * Bt[((n)&bRowMask)*Ktot + bOffB + kOff + k])
// base(r) = (r + (r/RPB)*EXTRA) * BSCALE;  Ae = (nHalf && n0>=nHalf) ? A2 : A.
// SPLITK: bz picks k-chunk; partial -> outp/outp2 (bf16).
// TRANS: out[bb*outBatchStride + (n0+f)*outLd + t_local] (bf16 via LDS repack).
// ROWPACK (BM=BN=128 only): row-major bf16 store via LDS repack + dwordx4.
template<int BM, int BN, bool RELU, bool OBF16, bool TRANS, bool SPLITK, int NH, bool ROWPACK>
__device__ __forceinline__ void gemm_core(
    int bx, int by, int bz, int nzTot, unsigned short* smem,
    const unsigned short* __restrict__ A,
    const unsigned short* __restrict__ A2,
    const unsigned short* __restrict__ Bt,
    const float* __restrict__ biasv,
    void* __restrict__ outp,
    void* __restrict__ outp2,
    int M, int Kchunk, int RPB, int EXTRA, int BSCALE,
    int nHalf, int bRowMask,
    long long bStrideB, long long outBatchStride, int outLd)
{
  constexpr int WM = BM / 2, WN = BN / 2;
  constexpr int NI = WM / 16, NJ = WN / 16;
  constexpr int AI = BM / 64;                 // glds instrs per wave per 32-chunk
  constexpr int BI = BN / 64;
  constexpr int SA1 = BM * 32, SB1 = BN * 32; // one 32-chunk region (shorts)
  unsigned short* sB0 = smem + NH * SA1;

  const int tid  = threadIdx.x;
  const int lane = tid & 63;
  const int wave = tid >> 6;
  const int wm = wave >> 1, wn = wave & 1;
  const int lr = lane & 15, quad = lane >> 4;

  const int r0 = bx * BM;
  const int n0 = by * BN;
  const int bb = r0 / RPB;
  const int Ktot = SPLITK ? Kchunk * nzTot : Kchunk;
  const int kOff = SPLITK ? bz * Kchunk : 0;
  const long long bOffB = (long long)bb * bStrideB;
  const unsigned short* Ae = (nHalf && n0 >= nHalf) ? A2 : A;

  const int srow = lane >> 2;
  const int sg = (lane & 3) ^ (srow & 3);     // XOR swizzle on fetch side
  const unsigned short* gA[AI]; unsigned short* ldsA[AI];
#pragma unroll
  for (int c = 0; c < AI; ++c) {
    int instr = c * 4 + wave;
    int row = instr * 16 + srow;
    int r = r0 + row; if (r > M - 1) r = M - 1;          // clamp partial tiles
    gA[c] = Ae + ((long long)r + (long long)(r / RPB) * EXTRA) * BSCALE + kOff + sg * 8;
    ldsA[c] = smem + instr * 512;
  }
  const unsigned short* gB[BI]; unsigned short* ldsB[BI];
#pragma unroll
  for (int c = 0; c < BI; ++c) {
    int instr = c * 4 + wave;
    int row = instr * 16 + srow;
    gB[c] = Bt + (long long)((n0 + row) & bRowMask) * Ktot + bOffB + kOff + sg * 8;
    ldsB[c] = sB0 + instr * 512;
  }

  int aoff[NI], boff[NJ];
#pragma unroll
  for (int i = 0; i < NI; ++i) {
    int rr = wm * WM + i * 16 + lr;
    aoff[i] = rr * 32 + ((quad ^ (rr & 3)) * 8);
  }
#pragma unroll
  for (int j = 0; j < NJ; ++j) {
    int rr = wn * WN + j * 16 + lr;
    boff[j] = rr * 32 + ((quad ^ (rr & 3)) * 8);
  }

  float4v acc[NI][NJ];
  const float4v z4 = {0.f, 0.f, 0.f, 0.f};
#pragma unroll
  for (int i = 0; i < NI; ++i)
#pragma unroll
    for (int j = 0; j < NJ; ++j) acc[i][j] = z4;

  for (int k0 = 0; k0 < Kchunk; k0 += 32 * NH) {
#pragma unroll
    for (int h = 0; h < NH; ++h) {
#pragma unroll
      for (int c = 0; c < AI; ++c)
        __builtin_amdgcn_global_load_lds((gu32*)(gA[c] + k0 + h * 32),
                                         (lu32*)(ldsA[c] + h * SA1), 16, 0, 0);
#pragma unroll
      for (int c = 0; c < BI; ++c)
        __builtin_amdgcn_global_load_lds((gu32*)(gB[c] + k0 + h * 32),
                                         (lu32*)(ldsB[c] + h * SB1), 16, 0, 0);
    }
    __syncthreads();
#pragma unroll
    for (int h = 0; h < NH; ++h) {
      short8 af[NI], bfr[NJ];
#pragma unroll
      for (int i = 0; i < NI; ++i) af[i] = *(const short8*)(smem + h * SA1 + aoff[i]);
#pragma unroll
      for (int j = 0; j < NJ; ++j) bfr[j] = *(const short8*)(sB0 + h * SB1 + boff[j]);
#pragma unroll
      for (int i = 0; i < NI; ++i)
#pragma unroll
        for (int j = 0; j < NJ; ++j)
          acc[i][j] = __builtin_amdgcn_mfma_f32_16x16x32_bf16(af[i], bfr[j], acc[i][j], 0, 0, 0);
    }
    __syncthreads();
  }

  if (TRANS) {
    // repack D (t,f) -> LDS (f-major, stride 136), then coalesced b128 stores
    unsigned short* Ts = smem;
#pragma unroll
    for (int j = 0; j < NJ; ++j) {
      int fr = wn * WN + j * 16 + lr;
      float bv = biasv[n0 + fr];
#pragma unroll
      for (int i = 0; i < NI; ++i) {
        int tr = wm * WM + i * 16 + quad * 4;
        unsigned long long pk = 0;
#pragma unroll
        for (int g = 0; g < 4; ++g) {
          float vv = acc[i][j][g] + bv;
          if (RELU) vv = fmaxf(vv, 0.f);
          pk |= (unsigned long long)f2bf(vv) << (16 * g);
        }
        *(unsigned long long*)(Ts + fr * 136 + tr) = pk;
      }
    }
    __syncthreads();
    int fr = tid >> 1, sgg = tid & 1;
    int t0l = r0 - bb * RPB;
    unsigned short* dst = (unsigned short*)outp + (long long)bb * outBatchStride
                        + (long long)(n0 + fr) * outLd + t0l + sgg * 64;
    const unsigned short* srcp = Ts + fr * 136 + sgg * 64;
#pragma unroll
    for (int u = 0; u < 8; ++u)
      *(uint4*)(dst + u * 8) = *(const uint4*)(srcp + u * 8);
  } else if (ROWPACK) {
    // row-major bf16 store via LDS (r-local row, stride 136) + dwordx4
    void* op = (SPLITK && bz) ? outp2 : outp;
    unsigned short* R = smem;
#pragma unroll
    for (int j = 0; j < NJ; ++j) {
      int cc = wn * WN + j * 16 + lr;
#pragma unroll
      for (int i = 0; i < NI; ++i) {
        int rrb = wm * WM + i * 16 + quad * 4;
#pragma unroll
        for (int g = 0; g < 4; ++g)
          R[(rrb + g) * 136 + cc] = f2bf(acc[i][j][g]);
      }
    }
    __syncthreads();
    int rloc = tid >> 1, half = tid & 1;
    unsigned short* dstp = (unsigned short*)op + (long long)(r0 + rloc) * outLd + n0 + half * 64;
    const unsigned short* srcp = R + rloc * 136 + half * 64;
#pragma unroll
    for (int u = 0; u < 8; ++u)
      *(uint4*)(dstp + u * 8) = *(const uint4*)(srcp + u * 8);
  } else {
    void* op = (SPLITK && bz) ? outp2 : outp;
#pragma unroll
    for (int j = 0; j < NJ; ++j) {
      int n_g = n0 + wn * WN + j * 16 + lr;
      float bv = biasv ? biasv[n_g] : 0.f;
#pragma unroll
      for (int i = 0; i < NI; ++i) {
        int r_base = r0 + wm * WM + i * 16 + quad * 4;
#pragma unroll
        for (int g = 0; g < 4; ++g) {
          int r_g = r_base + g;
          if (r_g >= M) continue;
          float v = acc[i][j][g] + bv;
          if (RELU) v = fmaxf(v, 0.f);
          long long oidx = (long long)r_g * outLd + n_g;
          if (OBF16) ((unsigned short*)op)[oidx] = f2bf(v);
          else       ((float*)op)[oidx] = v;
        }
      }
    }
  }
}

// Standalone GEMM wrapper (used for G).
template<int BM, int BN, bool RELU, bool OBF16, bool TRANS, bool SPLITK, int NH, bool ROWPACK>
__global__ __launch_bounds__(256)
void gemm_bt(const unsigned short* __restrict__ A,
             const unsigned short* __restrict__ A2,
             const unsigned short* __restrict__ Bt,
             const float* __restrict__ biasv,
             void* __restrict__ outp,
             void* __restrict__ outp2,
             int M, int Kchunk, int RPB, int EXTRA, int BSCALE,
             int nHalf, int bRowMask,
             long long bStrideB, long long outBatchStride, int outLd)
{
  constexpr int STAGE = NH * (BM * 32 + BN * 32);
  constexpr int REPK = (TRANS || ROWPACK) ? 128 * 136 : 0;
  constexpr int SMEMN = (REPK > STAGE) ? REPK : STAGE;
  __shared__ unsigned short smem[SMEMN];
  gemm_core<BM, BN, RELU, OBF16, TRANS, SPLITK, NH, ROWPACK>(
      blockIdx.x, blockIdx.y, blockIdx.z, gridDim.z, smem,
      A, A2, Bt, biasv, outp, outp2,
      M, Kchunk, RPB, EXTRA, BSCALE, nHalf, bRowMask,
      bStrideB, outBatchStride, outLd);
}

// Megakernel: blocks [0,1024) = conv1-w (TRANS gemm 128x128, grid 256x4);
//             blocks [1024,1284) = conv1-b (gemm 64x128, grid 65x4);
//             blocks [1284,5380) = cvt_x rows.
__global__ __launch_bounds__(256) void mega(
    const float* __restrict__ x,
    const unsigned short* __restrict__ zb,
    const unsigned short* __restrict__ w1T,
    const unsigned short* __restrict__ b1T,
    const float* __restrict__ wb1,
    const float* __restrict__ bb1,
    unsigned short* __restrict__ h1T,
    unsigned short* __restrict__ h1b,
    unsigned short* __restrict__ xs,
    unsigned short* __restrict__ xz,
    float* __restrict__ rs)
{
  __shared__ unsigned short smem[17408];   // max(128*136 repack, 16384 stage)
  int b = blockIdx.x;
  if (b < 1024) {
    // conv1-w -> h1T (TRANS, relu, NH=2): M=8*4096, K=256, A row=(r+2bb)*128
    gemm_core<128, 128, true, true, true, false, 2, false>(
        b & 255, b >> 8, 0, 1, smem,
        zb, nullptr, w1T, wb1, h1T, nullptr,
        32768, 256, 4096, 2, 128, 0, 0xFFFF, 0, 512ll * 4096, 4096);
  } else if (b < 1284) {
    int idx = b - 1024;
    // conv1-b (t<513): M=8*513, A row=(r+3585bb)*128 -> h1b bf16
    gemm_core<64, 128, true, true, false, false, 2, false>(
        idx % 65, idx / 65, 0, 1, smem,
        zb, nullptr, b1T, bb1, h1b, nullptr,
        4104, 256, 513, 3585, 128, 0, 0xFFFF, 0, 0, 512);
  } else {
    // cvt_x: xs[r,t]=bf16(x[r,t+1]) (0 at t=4095), xz[r,t]=bf16(x[r,t]) (0 at t=0),
    // rs[r]=sum_t f32(xs[r,t])
    float* red = (float*)smem;
    long long r = b - 1284;
    const float* xr = x + r * 4096;
    int t0 = threadIdx.x * 16;
    float v[17];
    const float4* xr4 = (const float4*)(xr + t0);
#pragma unroll
    for (int q = 0; q < 4; ++q) {
      float4 f = xr4[q];
      v[q * 4] = f.x; v[q * 4 + 1] = f.y; v[q * 4 + 2] = f.z; v[q * 4 + 3] = f.w;
    }
    v[16] = (t0 + 16 < 4096) ? xr[t0 + 16] : 0.f;
    unsigned int spk[8], zpk[8];
    float sum = 0.f;
#pragma unroll
    for (int q = 0; q < 8; ++q) {
      unsigned short s0 = f2bf(v[2 * q + 1]);
      unsigned short s1 = f2bf(v[2 * q + 2]);
      sum += bf2f(s0);
      sum += bf2f(s1);
      spk[q] = (unsigned int)s0 | ((unsigned int)s1 << 16);
      unsigned short z0 = (t0 == 0 && q == 0) ? (unsigned short)0 : f2bf(v[2 * q]);
      unsigned short z1 = f2bf(v[2 * q + 1]);
      zpk[q] = (unsigned int)z0 | ((unsigned int)z1 << 16);
    }
    *(uint4*)(xs + r * 4096 + t0)     = *(uint4*)(spk);
    *(uint4*)(xs + r * 4096 + t0 + 8) = *(uint4*)(spk + 4);
    *(uint4*)(xz + r * 4096 + t0)     = *(uint4*)(zpk);
    *(uint4*)(xz + r * 4096 + t0 + 8) = *(uint4*)(zpk + 4);
#pragma unroll
    for (int off = 32; off > 0; off >>= 1) sum += __shfl_down(sum, off);
    if ((threadIdx.x & 63) == 0) red[threadIdx.x >> 6] = sum;
    __syncthreads();
    if (threadIdx.x == 0) rs[r] = red[0] + red[1] + red[2] + red[3];
  }
}

// Fused final, 3 K-segments (K=3072), BK=128 (NH=4):
//   k in [0,1024):    A=p0[r,k],                 B=w2T[n,k]
//   k in [1024,2048): A=p1[r,k-1024],            B=w2T[n,k-1024]
//   k in [2048,3072): A=h1b[(r+r/512)*512+k'],   B=b2T[n,k']     (k'=k-2048)
// out[r,n] = acc + rs[r]*wb2[n] + bb2[n].  BM=BN=64, glds staging.
__global__ __launch_bounds__(256) void final_gemm3(
    const unsigned short* __restrict__ p0,
    const unsigned short* __restrict__ p1,
    const unsigned short* __restrict__ h1b,
    const unsigned short* __restrict__ w2T,
    const unsigned short* __restrict__ b2T,
    const float* __restrict__ rs,
    const float* __restrict__ wb2,
    const float* __restrict__ bb2,
    float* __restrict__ out)
{
  constexpr int SA1 = 64 * 32, SB1 = 64 * 32;
  __shared__ unsigned short smem[4 * SA1 + 4 * SB1];
  const int tid = threadIdx.x;
  const int lane = tid & 63, wave = tid >> 6;
  const int wm = wave >> 1, wn = wave & 1;
  const int lr = lane & 15, quad = lane >> 4;
  const int r0 = blockIdx.x * 64, n0 = blockIdx.y * 64;

  const int srow = lane >> 2;
  const int sg = (lane & 3) ^ (srow & 3);
  const int row = wave * 16 + srow;
  const int rA = r0 + row;
  const int rB = n0 + row;
  const unsigned short* aP[3] = {
    p0 + (long long)rA * 1024 + sg * 8,
    p1 + (long long)rA * 1024 + sg * 8,
    h1b + ((long long)rA + (rA >> 9)) * 512 + sg * 8 };
  const unsigned short* bP[3] = {
    w2T + (long long)rB * 1024 + sg * 8,
    w2T + (long long)rB * 1024 + sg * 8,
    b2T + (long long)rB * 1024 + sg * 8 };
  unsigned short* ldsA = smem + wave * 512;
  unsigned short* ldsB = smem + 4 * SA1 + wave * 512;

  int aoff[2], boff[2];
#pragma unroll
  for (int i = 0; i < 2; ++i) {
    int rr = wm * 32 + i * 16 + lr;
    aoff[i] = rr * 32 + ((quad ^ (rr & 3)) * 8);
    int nn = wn * 32 + i * 16 + lr;
    boff[i] = 4 * SA1 + nn * 32 + ((quad ^ (nn & 3)) * 8);
  }

  float4v acc[2][2];
  const float4v z4 = {0.f, 0.f, 0.f, 0.f};
  acc[0][0] = z4; acc[0][1] = z4; acc[1][0] = z4; acc[1][1] = z4;

  for (int k0 = 0; k0 < 3072; k0 += 128) {
    int seg = k0 >> 10;
    int kk = k0 & 1023;
#pragma unroll
    for (int h = 0; h < 4; ++h) {
      __builtin_amdgcn_global_load_lds((gu32*)(aP[seg] + kk + h * 32),
                                       (lu32*)(ldsA + h * SA1), 16, 0, 0);
      __builtin_amdgcn_global_load_lds((gu32*)(bP[seg] + kk + h * 32),
                                       (lu32*)(ldsB + h * SB1), 16, 0, 0);
    }
    __syncthreads();
#pragma unroll
    for (int h = 0; h < 4; ++h) {
      short8 af[2], bfr[2];
      af[0] = *(const short8*)(smem + h * SA1 + aoff[0]);
      af[1] = *(const short8*)(smem + h * SA1 + aoff[1]);
      bfr[0] = *(const short8*)(smem + h * SB1 + boff[0]);
      bfr[1] = *(const short8*)(smem + h * SB1 + boff[1]);
#pragma unroll
      for (int i = 0; i < 2; ++i)
#pragma unroll
        for (int j = 0; j < 2; ++j)
          acc[i][j] = __builtin_amdgcn_mfma_f32_16x16x32_bf16(af[i], bfr[j], acc[i][j], 0, 0, 0);
    }
    __syncthreads();
  }

#pragma unroll
  for (int j = 0; j < 2; ++j) {
    int n_g = n0 + wn * 32 + j * 16 + lr;
    float w2b = wb2[n_g], bbv = bb2[n_g];
#pragma unroll
    for (int i = 0; i < 2; ++i) {
      int rb = r0 + wm * 32 + i * 16 + quad * 4;
#pragma unroll
      for (int g = 0; g < 4; ++g) {
        int r_g = rb + g;
        out[(long long)r_g * 512 + n_g] = acc[i][j][g] + rs[r_g] * w2b + bbv;
      }
    }
  }
}

extern "C" void kernel_launch(void* const* d_in, const int* in_sizes, int n_in,
                              void* d_out, int out_size, void* d_ws, size_t ws_size,
                              hipStream_t stream) {
  const float* x   = (const float*)d_in[0];
  const float* z   = (const float*)d_in[1];
  const float* ww1 = (const float*)d_in[2];
  const float* wb1 = (const float*)d_in[3];
  const float* ww2 = (const float*)d_in[4];
  const float* wb2 = (const float*)d_in[5];
  const float* bw1 = (const float*)d_in[6];
  const float* bb1 = (const float*)d_in[7];
  const float* bw2 = (const float*)d_in[8];
  const float* bb2 = (const float*)d_in[9];

  char* ws = (char*)d_ws;
  unsigned short* xs  = (unsigned short*)ws; ws += 16777216ll * 2;  // (4096,4096) shifted bf16
  unsigned short* xz  = (unsigned short*)ws; ws += 16777216ll * 2;  // (4096,4096) t0-zeroed bf16
  unsigned short* zb  = (unsigned short*)ws; ws += 4196352ll  * 2;  // (8,4098,128) bf16; reused as p0
  unsigned short* h1T = (unsigned short*)ws; ws += 16777216ll * 2;  // (8,512,4096) h1 transposed bf16
  unsigned short* h1b = (unsigned short*)ws; ws += 2101248ll  * 2;  // (8,513,512) bias-path h1 bf16
  unsigned short* w2T = (unsigned short*)ws; ws += 524288ll * 2;    // (512,1024)
  unsigned short* b2T = (unsigned short*)ws; ws += 524288ll * 2;
  float* rs = (float*)ws;                    ws += 4096ll * 4;      // rowsum(xs)
  char* tail = ws;
  // w1T/b1T live until mega completes, then tail becomes p1
  unsigned short* w1T = (unsigned short*)tail;                      // (512,256)
  unsigned short* b1T = (unsigned short*)tail + 131072;             // (512,256)
  unsigned short* p0  = zb;                                         // (4096,1024) bf16 (zb dead by then)
  unsigned short* p1  = (unsigned short*)tail;                      // (4096,1024) bf16

  // 1) weights + z -> bf16 transposed
  prep_w<<<21512, 256, 0, stream>>>(ww1, ww2, bw1, bw2, z, w1T, w2T, b1T, b2T, zb);
  // 2) megakernel: conv1-w (TRANS) + conv1-b + cvt_x overlapped in one dispatch
  mega<<<5380, 256, 0, stream>>>(x, zb, w1T, b1T, wb1, bb1, h1T, h1b, xs, xz, rs);
  // 3) G = [xs ; xz] @ h1T^T, 128^2 tiles, BK=128, split-K x2 -> p0,p1 (bf16,
  //    ROWPACK coalesced stores): M=4096, N=1024, Kchunk=2048, bRowMask=511
  gemm_bt<128, 128, false, true, false, true, 4, true><<<dim3(32, 8, 2), 256, 0, stream>>>(
      xs, xz, h1T, nullptr, p0, p1,
      4096, 2048, 512, 0, 4096, 512, 511, 512ll * 4096, 0, 1024);
  // 4) out = p0@w2 + p1@w2 + h1b-pair@b2 + rs x wb2 + bb2  (K=3072 fused, BK=128)
  final_gemm3<<<dim3(64, 8), 256, 0, stream>>>(
      p0, p1, h1b, w2T, b2T, rs, wb2, bb2, (float*)d_out);
}